// Round 3
// baseline (618.419 us; speedup 1.0000x reference)
//
#include <hip/hip_runtime.h>
#include <math.h>

#define BB 64
#define TT 1024
#define DD 32
#define GG 128   // 4*D
#define VOCABN 10000
#define QLEN 100

typedef short short8 __attribute__((ext_vector_type(8)));   // 8 bf16 in 4 VGPRs
typedef float floatx4 __attribute__((ext_vector_type(4)));
typedef float floatx2 __attribute__((ext_vector_type(2)));
typedef unsigned short u16;

__device__ __forceinline__ float fsig(float x) {
    return __builtin_amdgcn_rcpf(1.0f + __expf(-x));
}
__device__ __forceinline__ float readlane_f(float v, int l) {
    return __int_as_float(__builtin_amdgcn_readlane(__float_as_int(v), l));
}
__device__ __forceinline__ u16 f2bf_rne(float x) {
    unsigned u = __float_as_uint(x);
    u += 0x7FFF + ((u >> 16) & 1);
    return (u16)(u >> 16);
}
__device__ __forceinline__ float bf2f(u16 s) {
    return __uint_as_float(((unsigned)s) << 16);
}
// packed fma: one v_pk_fma_f32 for the {a,b}-gate pair. IEEE fma per half ->
// bit-exact vs two fmaf.
__device__ __forceinline__ floatx2 fma2(float s, floatx2 w, floatx2 acc) {
    return __builtin_elementwise_fma((floatx2){s, s}, w, acc);
}

// ---------------------------------------------------------------------------
// Kernel 1: LSTM scan — R20: R19 + 2-batch interleave per wave + v_pk_fma_f32.
// R19 post-mortem: per-step 600 cyc, issue ~230, chain ~150 -> ~370 cyc of
// single-wave latency bubbles. Fill them with a SECOND batch's independent
// chain in the same issue stream (weights shared, only state duplicated), and
// halve dot issue with packed f32 fma (float2 over the ga/gb gate pair).
// Per-batch arithmetic is op-for-op identical to R19 (same combine order,
// same fsig/tanh forms, same permlane32_swap exchange) -> bit-exact.
// Grid: BB/2 consumer blocks + 1 queue block. 2 waves: consumer + producer
// (producer handles both batches; ~2100 cyc/chunk < consumer ~3400).
// ---------------------------------------------------------------------------
#define UU 8
__global__
__attribute__((amdgpu_flat_work_group_size(128, 128)))
__attribute__((amdgpu_waves_per_eu(1, 1)))
void k_lstm_scan(const int* __restrict__ ids,
                 const float* __restrict__ emb,
                 const float* __restrict__ klstm,
                 const float* __restrict__ bias,
                 const float* __restrict__ rk,
                 float* __restrict__ hout,
                 int* __restrict__ list,
                 float* __restrict__ outq) {
    const int blk = blockIdx.x;
    const int tid = threadIdx.x;
    const int wv = tid >> 6;   // wave 0 consumer / wave 1 producer
    const int l = tid & 63;
    if (blk >= BB / 2) {
        if (wv != 0) return;
        // ---- fused zero-index queue (single wave, no barriers) ----
        const int4* v4 = (const int4*)ids;
        const int C4 = (BB * TT) / 4 / 64;
        const int b4 = l * C4;
        int cnt = 0;
#pragma unroll 4
        for (int i = 0; i < C4; ++i) {
            int4 v = v4[b4 + i];
            cnt += (v.x == 0 || (unsigned)v.x >= VOCABN);
            cnt += (v.y == 0 || (unsigned)v.y >= VOCABN);
            cnt += (v.z == 0 || (unsigned)v.z >= VOCABN);
            cnt += (v.w == 0 || (unsigned)v.w >= VOCABN);
        }
        int scan = cnt;
#pragma unroll
        for (int o = 1; o < 64; o <<= 1) {
            int nn = __shfl_up(scan, o);
            if (l >= o) scan += nn;
        }
        const int total = __shfl(scan, 63);
        int off = scan - cnt;
        const int base = l * (C4 * 4);
#pragma unroll 4
        for (int i = 0; i < C4; ++i) {
            int4 v = v4[b4 + i];
            if (v.x == 0 || (unsigned)v.x >= VOCABN) list[off++] = base + 4 * i;
            if (v.y == 0 || (unsigned)v.y >= VOCABN) list[off++] = base + 4 * i + 1;
            if (v.z == 0 || (unsigned)v.z >= VOCABN) list[off++] = base + 4 * i + 2;
            if (v.w == 0 || (unsigned)v.w >= VOCABN) list[off++] = base + 4 * i + 3;
        }
        __threadfence();
        const int Kc = total < QLEN ? total : QLEN;
        for (int t = l; t < QLEN; t += 64) {
            float ii = -1.0f, jj = -1.0f;
            if (t >= QLEN - Kc) {
                int pos = list[total - QLEN + t];
                ii = (float)(pos >> 10);
                jj = (float)(pos & (TT - 1));
            }
            outq[2 * t] = ii;
            outq[2 * t + 1] = jj;
        }
        return;
    }

    const int b0 = 2 * blk, b1 = 2 * blk + 1;
    __shared__ float ring[2][2][UU][GG];   // 16 KB: [sel][batch][u][gate]
    const int* idsb0 = ids + b0 * TT;
    const int* idsb1 = ids + b1 * TT;

    if (wv == 1) {
        // ------------ producer: xg for BOTH batches, 8 tokens ahead ---------
        const int ja = l, jb = l + 64;
        floatx2 kp[DD];
#pragma unroll
        for (int d2 = 0; d2 < DD; ++d2)
            kp[d2] = (floatx2){klstm[d2 * GG + ja], klstm[d2 * GG + jb]};
        const floatx2 bj = (floatx2){bias[ja], bias[jb]};
        const int dd = l & 31;

#define PROD_TOKEN(SEL, U, BT, EV)                                           \
        {                                                                    \
            floatx2 z0 = bj;                                                 \
            floatx2 z1 = {0.f, 0.f}, z2 = {0.f, 0.f}, z3 = {0.f, 0.f};       \
            _Pragma("unroll")                                                \
            for (int k = 0; k < DD; k += 4) {                                \
                float e0 = readlane_f(EV, k);                                \
                float e1 = readlane_f(EV, k + 1);                            \
                float e2 = readlane_f(EV, k + 2);                            \
                float e3 = readlane_f(EV, k + 3);                            \
                z0 = fma2(e0, kp[k], z0);                                    \
                z1 = fma2(e1, kp[k + 1], z1);                                \
                z2 = fma2(e2, kp[k + 2], z2);                                \
                z3 = fma2(e3, kp[k + 3], z3);                                \
            }                                                                \
            floatx2 zf = (z0 + z1) + (z2 + z3);                              \
            ring[SEL][BT][U][ja] = zf.x;                                     \
            ring[SEL][BT][U][jb] = zf.y;                                     \
        }

        {
            int i0 = idsb0[0]; if ((unsigned)i0 >= VOCABN) i0 = 0;
            int i1 = idsb1[0]; if ((unsigned)i1 >= VOCABN) i1 = 0;
            float ec0 = emb[i0 * DD + dd];
            float ec1 = emb[i1 * DD + dd];
#pragma unroll
            for (int u = 0; u < UU; ++u) {
                float en0 = 0.f, en1 = 0.f;
                if (u + 1 < UU) {
                    int n0 = idsb0[u + 1]; if ((unsigned)n0 >= VOCABN) n0 = 0;
                    int n1 = idsb1[u + 1]; if ((unsigned)n1 >= VOCABN) n1 = 0;
                    en0 = emb[n0 * DD + dd];
                    en1 = emb[n1 * DD + dd];
                }
                PROD_TOKEN(0, u, 0, ec0)
                PROD_TOKEN(0, u, 1, ec1)
                ec0 = en0; ec1 = en1;
            }
        }
        __syncthreads();
        int sel = 0;
        for (int t0 = 0; t0 < TT; t0 += UU) {
            if (t0 + UU < TT) {
                const int s = sel ^ 1;
                int i0 = idsb0[t0 + UU]; if ((unsigned)i0 >= VOCABN) i0 = 0;
                int i1 = idsb1[t0 + UU]; if ((unsigned)i1 >= VOCABN) i1 = 0;
                float ec0 = emb[i0 * DD + dd];
                float ec1 = emb[i1 * DD + dd];
#pragma unroll
                for (int u = 0; u < UU; ++u) {
                    float en0 = 0.f, en1 = 0.f;
                    if (u + 1 < UU) {
                        int tn = t0 + UU + u + 1;
                        if (tn > TT - 1) tn = TT - 1;
                        int n0 = idsb0[tn]; if ((unsigned)n0 >= VOCABN) n0 = 0;
                        int n1 = idsb1[tn]; if ((unsigned)n1 >= VOCABN) n1 = 0;
                        en0 = emb[n0 * DD + dd];
                        en1 = emb[n1 * DD + dd];
                    }
                    PROD_TOKEN(s, u, 0, ec0)
                    PROD_TOKEN(s, u, 1, ec1)
                    ec0 = en0; ec1 = en1;
                }
            }
            __syncthreads();
            sel ^= 1;
        }
#undef PROD_TOKEN
        return;
    }

    // -------- consumer: TWO interleaved R19-exact scans, xg from ring -------
    const int d = l & 31;
    const bool hi = l >= 32;
    const int ga = (hi ? 32 : 0) + d;
    const int gb = (hi ? 96 : 64) + d;
    floatx2 rkp[DD];
#pragma unroll
    for (int k = 0; k < DD; ++k)
        rkp[k] = (floatx2){rk[k * GG + ga], rk[k * GG + gb]};
    float* hb0 = hout + (size_t)b0 * TT * DD;
    float* hb1 = hout + (size_t)b1 * TT * DD;

    float h0 = 0.0f, c0s = 0.0f, h1 = 0.0f, c1s = 0.0f;
    float hreg0[UU], hreg1[UU];
    __syncthreads();   // matches producer prologue barrier
    int sel = 0;
    for (int t0 = 0; t0 < TT; t0 += UU) {
        // flush previous chunk's h first: stores retire under this chunk's
        // compute, so the chunk-end barrier's vmcnt(0) drain is free.
        if (t0 && !hi) {
#pragma unroll
            for (int u = 0; u < UU; ++u) {
                hb0[(size_t)(t0 - UU + u) * DD + d] = hreg0[u];
                hb1[(size_t)(t0 - UU + u) * DD + d] = hreg1[u];
            }
        }
        float pa0[UU], pb0[UU], pa1[UU], pb1[UU];
#pragma unroll
        for (int u = 0; u < UU; ++u) {
            pa0[u] = ring[sel][0][u][ga];
            pb0[u] = ring[sel][0][u][gb];
            pa1[u] = ring[sel][1][u][ga];
            pb1[u] = ring[sel][1][u][gb];
        }
#pragma unroll
        for (int u = 0; u < UU; ++u) {
            floatx2 x0_0 = {pa0[u], pb0[u]};
            floatx2 x0_1 = {0.f, 0.f}, x0_2 = {0.f, 0.f}, x0_3 = {0.f, 0.f};
            floatx2 x1_0 = {pa1[u], pb1[u]};
            floatx2 x1_1 = {0.f, 0.f}, x1_2 = {0.f, 0.f}, x1_3 = {0.f, 0.f};
#pragma unroll
            for (int k = 0; k < DD; k += 4) {
                float e0 = readlane_f(h0, k);
                float e1 = readlane_f(h0, k + 1);
                float e2 = readlane_f(h0, k + 2);
                float e3 = readlane_f(h0, k + 3);
                float f0 = readlane_f(h1, k);
                float f1 = readlane_f(h1, k + 1);
                float f2 = readlane_f(h1, k + 2);
                float f3 = readlane_f(h1, k + 3);
                x0_0 = fma2(e0, rkp[k],     x0_0);
                x0_1 = fma2(e1, rkp[k + 1], x0_1);
                x0_2 = fma2(e2, rkp[k + 2], x0_2);
                x0_3 = fma2(e3, rkp[k + 3], x0_3);
                x1_0 = fma2(f0, rkp[k],     x1_0);
                x1_1 = fma2(f1, rkp[k + 1], x1_1);
                x1_2 = fma2(f2, rkp[k + 2], x1_2);
                x1_3 = fma2(f3, rkp[k + 3], x1_3);
            }
            floatx2 zf0 = (x0_0 + x0_1) + (x0_2 + x0_3);
            floatx2 zf1 = (x1_0 + x1_1) + (x1_2 + x1_3);
            // ---- batch0 activation (R19-exact) ----
            {
                float za = zf0.x, zb = zf0.y;
                float a = fsig(za);                       // sig(i) lo / sig(f) hi
                float zbm = hi ? zb : 2.0f * zb;
                float s2 = fsig(zbm);
                float bv = hi ? s2 : 2.0f * s2 - 1.0f;    // sig(o) hi / tanh(g) lo
                auto r1 = __builtin_amdgcn_permlane32_swap(
                    __float_as_int(bv), __float_as_int(a), false, false);
                auto r2 = __builtin_amdgcn_permlane32_swap(
                    __float_as_int(a), __float_as_int(bv), false, false);
                float fg = __int_as_float(r1[0]);
                float og = __int_as_float(r2[0]);
                c0s = fmaf(fg, c0s, a * bv);
                float tc = 2.0f * fsig(2.0f * c0s) - 1.0f;
                h0 = og * tc;
                hreg0[u] = h0;
            }
            // ---- batch1 activation (R19-exact) ----
            {
                float za = zf1.x, zb = zf1.y;
                float a = fsig(za);
                float zbm = hi ? zb : 2.0f * zb;
                float s2 = fsig(zbm);
                float bv = hi ? s2 : 2.0f * s2 - 1.0f;
                auto r1 = __builtin_amdgcn_permlane32_swap(
                    __float_as_int(bv), __float_as_int(a), false, false);
                auto r2 = __builtin_amdgcn_permlane32_swap(
                    __float_as_int(a), __float_as_int(bv), false, false);
                float fg = __int_as_float(r1[0]);
                float og = __int_as_float(r2[0]);
                c1s = fmaf(fg, c1s, a * bv);
                float tc = 2.0f * fsig(2.0f * c1s) - 1.0f;
                h1 = og * tc;
                hreg1[u] = h1;
            }
        }
        __syncthreads();
        sel ^= 1;
    }
    if (!hi) {
#pragma unroll
        for (int u = 0; u < UU; ++u) {
            hb0[(size_t)(TT - UU + u) * DD + d] = hreg0[u];
            hb1[(size_t)(TT - UU + u) * DD + d] = hreg1[u];
        }
    }
}

// ---------------------------------------------------------------------------
// Kernel 2: cvt — R13 version (XCD-swizzled, 256 blocks), unchanged.
// ---------------------------------------------------------------------------
__global__ __launch_bounds__(256) void k_cvt(const float* __restrict__ h,
                                             u16* __restrict__ hh, u16* __restrict__ hl,
                                             u16* __restrict__ th, u16* __restrict__ tl) {
    const int b = blockIdx.x & 63;
    const int seg = blockIdx.x >> 6;
    const int tid = threadIdx.x;
    const float* hsrc = h + (size_t)b * TT * DD;
    const size_t rb = (size_t)b * TT * DD;
    const size_t tb = (size_t)b * DD * TT;
    __shared__ float tile[64][33];
    for (int t0 = seg * 256; t0 < seg * 256 + 256; t0 += 64) {
#pragma unroll
        for (int n = 0; n < 2; ++n) {
            int idx = tid + n * 256;
            int row = idx >> 3, c4 = idx & 7;
            float4 v = *(const float4*)&hsrc[(size_t)(t0 + row) * DD + c4 * 4];
            float xs[4] = {v.x, v.y, v.z, v.w};
            u16 hi4[4], lo4[4];
#pragma unroll
            for (int i = 0; i < 4; ++i) {
                tile[row][c4 * 4 + i] = xs[i];
                hi4[i] = f2bf_rne(xs[i]);
                lo4[i] = f2bf_rne(xs[i] - bf2f(hi4[i]));
            }
            ushort4 hv = {hi4[0], hi4[1], hi4[2], hi4[3]};
            ushort4 lv = {lo4[0], lo4[1], lo4[2], lo4[3]};
            *(ushort4*)&hh[rb + (size_t)(t0 + row) * DD + c4 * 4] = hv;
            *(ushort4*)&hl[rb + (size_t)(t0 + row) * DD + c4 * 4] = lv;
        }
        __syncthreads();
#pragma unroll
        for (int n = 0; n < 8; ++n) {
            int flat = tid + n * 256;
            int dd = flat >> 6, tt = flat & 63;
            float x = tile[tt][dd];
            u16 hv = f2bf_rne(x);
            u16 lv = f2bf_rne(x - bf2f(hv));
            th[tb + (size_t)dd * TT + t0 + tt] = hv;
            tl[tb + (size_t)dd * TT + t0 + tt] = lv;
        }
        __syncthreads();
    }
}

// ---------------------------------------------------------------------------
// Kernel 3: attention on MFMA — R16 P-lag version (absmax 0.0, measured).
// ---------------------------------------------------------------------------
__global__ __launch_bounds__(256, 4) void k_attn(const u16* __restrict__ hh,
                                                 const u16* __restrict__ hl,
                                                 const u16* __restrict__ th,
                                                 const u16* __restrict__ tl,
                                                 float* __restrict__ ctx) {
    __shared__ u16 plds[4][2][16 * 40];   // per-wave double-buffered P
    const int tid = threadIdx.x;
    const int w = tid >> 6;
    const int l = tid & 63;
    const int m = l & 15;
    const int g = l >> 4;
    const int b = blockIdx.x & 63;              // XCD swizzle: XCD = b % 8
    const int qt = (blockIdx.x >> 6) * 4 + w;
    const int q0 = qt * 16;
    const size_t rb = (size_t)b * TT * DD;
    const size_t tb = (size_t)b * DD * TT;

    const short8 Qh = *(const short8*)&hh[rb + (size_t)(q0 + m) * DD + g * 8];
    const short8 Ql = *(const short8*)&hl[rb + (size_t)(q0 + m) * DD + g * 8];
    short8 ONES;
#pragma unroll
    for (int j = 0; j < 8; ++j) ONES[j] = (short)0x3F80;

    floatx4 c0 = {0.f, 0.f, 0.f, 0.f};
    floatx4 c1 = {0.f, 0.f, 0.f, 0.f};
    floatx4 la = {0.f, 0.f, 0.f, 0.f};

#define S_BLOCK(KH_A, KL_A, KH_B, KL_B, SA, SB)                               \
    SA = __builtin_amdgcn_mfma_f32_16x16x32_bf16(Qh, KH_A, SA, 0, 0, 0);      \
    SA = __builtin_amdgcn_mfma_f32_16x16x32_bf16(Qh, KL_A, SA, 0, 0, 0);      \
    SA = __builtin_amdgcn_mfma_f32_16x16x32_bf16(Ql, KH_A, SA, 0, 0, 0);      \
    SB = __builtin_amdgcn_mfma_f32_16x16x32_bf16(Qh, KH_B, SB, 0, 0, 0);      \
    SB = __builtin_amdgcn_mfma_f32_16x16x32_bf16(Qh, KL_B, SB, 0, 0, 0);      \
    SB = __builtin_amdgcn_mfma_f32_16x16x32_bf16(Ql, KH_B, SB, 0, 0, 0);

    // ---- kp = 0: S + exp + write slot0; no PV yet ----
    {
        short8 KhA = *(const short8*)&hh[rb + (size_t)(m) * DD + g * 8];
        short8 KlA = *(const short8*)&hl[rb + (size_t)(m) * DD + g * 8];
        short8 KhB = *(const short8*)&hh[rb + (size_t)(16 + m) * DD + g * 8];
        short8 KlB = *(const short8*)&hl[rb + (size_t)(16 + m) * DD + g * 8];
        floatx4 sA = {0.f, 0.f, 0.f, 0.f};
        floatx4 sB = {0.f, 0.f, 0.f, 0.f};
        S_BLOCK(KhA, KlA, KhB, KlB, sA, sB)
        u16* lds0 = plds[w][0];
#pragma unroll
        for (int r = 0; r < 4; ++r) {
            lds0[(g * 4 + r) * 40 + m]      = f2bf_rne(__expf(sA[r]));
            lds0[(g * 4 + r) * 40 + 16 + m] = f2bf_rne(__expf(sB[r]));
        }
    }
    // preload V_0 (used at kp=1) and K_1
    short8 Vh0 = *(const short8*)&th[tb + (size_t)m * TT + g * 8];
    short8 Vl0 = *(const short8*)&tl[tb + (size_t)m * TT + g * 8];
    short8 Vh1 = *(const short8*)&th[tb + (size_t)(16 + m) * TT + g * 8];
    short8 Vl1 = *(const short8*)&tl[tb + (size_t)(16 + m) * TT + g * 8];
    short8 KhA = *(const short8*)&hh[rb + (size_t)(32 + m) * DD + g * 8];
    short8 KlA = *(const short8*)&hl[rb + (size_t)(32 + m) * DD + g * 8];
    short8 KhB = *(const short8*)&hh[rb + (size_t)(48 + m) * DD + g * 8];
    short8 KlB = *(const short8*)&hl[rb + (size_t)(48 + m) * DD + g * 8];

#pragma unroll 1
    for (int kp = 1; kp < 32; ++kp) {
        const int knK = (kp < 31) ? (kp + 1) * 32 : 0;
        const int knV = kp * 32;
        short8 nKhA = *(const short8*)&hh[rb + (size_t)(knK + m) * DD + g * 8];
        short8 nKlA = *(const short8*)&hl[rb + (size_t)(knK + m) * DD + g * 8];
        short8 nKhB = *(const short8*)&hh[rb + (size_t)(knK + 16 + m) * DD + g * 8];
        short8 nKlB = *(const short8*)&hl[rb + (size_t)(knK + 16 + m) * DD + g * 8];
        short8 nVh0 = *(const short8*)&th[tb + (size_t)m * TT + knV + g * 8];
        short8 nVl0 = *(const short8*)&tl[tb + (size_t)m * TT + knV + g * 8];
        short8 nVh1 = *(const short8*)&th[tb + (size_t)(16 + m) * TT + knV + g * 8];
        short8 nVl1 = *(const short8*)&tl[tb + (size_t)(16 + m) * TT + knV + g * 8];

        floatx4 sA = {0.f, 0.f, 0.f, 0.f};
        floatx4 sB = {0.f, 0.f, 0.f, 0.f};
        S_BLOCK(KhA, KlA, KhB, KlB, sA, sB)

        const short8 P = *(const short8*)&plds[w][(kp - 1) & 1][m * 40 + g * 8];

        u16 pe[8];
#pragma unroll
        for (int r = 0; r < 4; ++r) {
            pe[r]     = f2bf_rne(__expf(sA[r]));
            pe[4 + r] = f2bf_rne(__expf(sB[r]));
        }

        c0 = __builtin_amdgcn_mfma_f32_16x16x32_bf16(P, Vh0, c0, 0, 0, 0);
        c0 = __builtin_amdgcn_mfma_f32_16x16x32_bf16(P, Vl0, c0, 0, 0, 0);
        c1 = __builtin_amdgcn_mfma_f32_16x16x32_bf16(P, Vh1, c1, 0, 0, 0);
        c1 = __builtin_amdgcn_mfma_f32_16x16x32_bf16(P, Vl1, c1, 0, 0, 0);
        la = __builtin_amdgcn_mfma_f32_16x16x32_bf16(P, ONES, la, 0, 0, 0);

        u16* lds = plds[w][kp & 1];
#pragma unroll
        for (int r = 0; r < 4; ++r) {
            lds[(g * 4 + r) * 40 + m]      = pe[r];
            lds[(g * 4 + r) * 40 + 16 + m] = pe[4 + r];
        }

        KhA = nKhA; KlA = nKlA; KhB = nKhB; KlB = nKlB;
        Vh0 = nVh0; Vl0 = nVl0; Vh1 = nVh1; Vl1 = nVl1;
    }
    // epilogue: PV of kp=31
    {
        const short8 P = *(const short8*)&plds[w][31 & 1][m * 40 + g * 8];
        c0 = __builtin_amdgcn_mfma_f32_16x16x32_bf16(P, Vh0, c0, 0, 0, 0);
        c0 = __builtin_amdgcn_mfma_f32_16x16x32_bf16(P, Vl0, c0, 0, 0, 0);
        c1 = __builtin_amdgcn_mfma_f32_16x16x32_bf16(P, Vh1, c1, 0, 0, 0);
        c1 = __builtin_amdgcn_mfma_f32_16x16x32_bf16(P, Vl1, c1, 0, 0, 0);
        la = __builtin_amdgcn_mfma_f32_16x16x32_bf16(P, ONES, la, 0, 0, 0);
    }
#undef S_BLOCK
#pragma unroll
    for (int r = 0; r < 4; ++r) {
        float linv = __builtin_amdgcn_rcpf(la[r]);
        float* crow = ctx + (size_t)b * TT * DD + (size_t)(q0 + g * 4 + r) * DD;
        crow[m]      = c0[r] * linv;
        crow[16 + m] = c1[r] * linv;
    }
}

// ---------------------------------------------------------------------------
// Kernel 4: ymlp — R13 version, unchanged.
// ---------------------------------------------------------------------------
__global__ __launch_bounds__(256) void k_ymlp(const float* __restrict__ ctx,
                                              const float* __restrict__ h,
                                              const float* __restrict__ W1,
                                              const float* __restrict__ b1,
                                              const float* __restrict__ W2,
                                              const float* __restrict__ b2,
                                              float* __restrict__ out) {
    const int b = blockIdx.x;
    const int tid = threadIdx.x;
    __shared__ __align__(16) float cs[128 * DD];
    __shared__ __align__(16) float hs[128 * DD];
    const float* cb = ctx + (size_t)b * TT * DD;
    const float* hb = h + (size_t)b * TT * DD;
    const int e = tid & 31;
    const int d4 = (tid >> 5) * 4;
    float acc[4] = {0.f, 0.f, 0.f, 0.f};
    for (int kt = 0; kt < 8; ++kt) {
        const float4* s1 = (const float4*)(cb + (size_t)kt * 128 * DD);
        const float4* s2 = (const float4*)(hb + (size_t)kt * 128 * DD);
        float4* t1 = (float4*)cs;
        float4* t2 = (float4*)hs;
#pragma unroll
        for (int n = 0; n < 4; ++n) {
            t1[tid + n * 256] = s1[tid + n * 256];
            t2[tid + n * 256] = s2[tid + n * 256];
        }
        __syncthreads();
#pragma unroll 2
        for (int s = 0; s < 128; ++s) {
            float hv = hs[s * DD + e];
            float4 cv = *(const float4*)&cs[s * DD + d4];
            acc[0] = fmaf(cv.x, hv, acc[0]);
            acc[1] = fmaf(cv.y, hv, acc[1]);
            acc[2] = fmaf(cv.z, hv, acc[2]);
            acc[3] = fmaf(cv.w, hv, acc[3]);
        }
        __syncthreads();
    }
    __shared__ float ys[DD][DD];
#pragma unroll
    for (int r = 0; r < 4; ++r) ys[d4 + r][e] = acc[r];
    __syncthreads();
    __shared__ float yr[DD][33];
#pragma unroll
    for (int r = 0; r < 4; ++r) {
        float v = b1[e];
#pragma unroll
        for (int ee = 0; ee < DD; ++ee) v += ys[d4 + r][ee] * W1[ee * DD + e];
        yr[d4 + r][e] = fmaxf(v, 0.0f);
    }
    __syncthreads();
    if (tid < DD) {
        float v = b2[0];
#pragma unroll
        for (int ee = 0; ee < DD; ++ee) v += yr[tid][ee] * W2[ee];
        out[b * DD + tid] = 1.0f / (1.0f + expf(-v));
    }
}

// ---------------------------------------------------------------------------
extern "C" void kernel_launch(void* const* d_in, const int* in_sizes, int n_in,
                              void* d_out, int out_size, void* d_ws, size_t ws_size,
                              hipStream_t stream) {
    const int* ids   = (const int*)d_in[0];
    const float* emb = (const float*)d_in[1];
    const float* kl  = (const float*)d_in[2];
    const float* rk  = (const float*)d_in[3];
    const float* bl  = (const float*)d_in[4];
    const float* W1  = (const float*)d_in[5];
    const float* b1  = (const float*)d_in[6];
    const float* W2  = (const float*)d_in[7];
    const float* b2  = (const float*)d_in[8];
    float* out = (float*)d_out;

    char* ws = (char*)d_ws;
    const size_t H_ELEMS = (size_t)BB * TT * DD;   // 2,097,152
    u16* hh   = (u16*)ws;
    u16* hl   = (u16*)(ws + H_ELEMS * 2);
    u16* th   = (u16*)(ws + H_ELEMS * 4);
    u16* tl   = (u16*)(ws + H_ELEMS * 6);
    float* h  = (float*)(ws + H_ELEMS * 8);
    float* ctx = (float*)(ws + H_ELEMS * 8 + H_ELEMS * 4);
    int* list = (int*)(ws + H_ELEMS * 8 + H_ELEMS * 8);

    k_lstm_scan<<<BB / 2 + 1, 128, 0, stream>>>(ids, emb, kl, bl, rk, h, list, out + BB * DD);
    k_cvt<<<256, 256, 0, stream>>>(h, hh, hl, th, tl);
    k_attn<<<BB * 16, 256, 0, stream>>>(hh, hl, th, tl, ctx);
    k_ymlp<<<BB, 256, 0, stream>>>(ctx, h, W1, b1, W2, b2, out);
}

// Round 4
// 431.353 us; speedup vs baseline: 1.4337x; 1.4337x over previous
//
#include <hip/hip_runtime.h>
#include <math.h>

#define BB 64
#define TT 1024
#define DD 32
#define GG 128   // 4*D
#define VOCABN 10000
#define QLEN 100

typedef short short8 __attribute__((ext_vector_type(8)));   // 8 bf16 in 4 VGPRs
typedef float floatx4 __attribute__((ext_vector_type(4)));
typedef float floatx2 __attribute__((ext_vector_type(2)));
typedef unsigned short u16;

__device__ __forceinline__ float fsig(float x) {
    return __builtin_amdgcn_rcpf(1.0f + __expf(-x));
}
__device__ __forceinline__ float readlane_f(float v, int l) {
    return __int_as_float(__builtin_amdgcn_readlane(__float_as_int(v), l));
}
__device__ __forceinline__ u16 f2bf_rne(float x) {
    unsigned u = __float_as_uint(x);
    u += 0x7FFF + ((u >> 16) & 1);
    return (u16)(u >> 16);
}
__device__ __forceinline__ float bf2f(u16 s) {
    return __uint_as_float(((unsigned)s) << 16);
}
// packed fma: one v_pk_fma_f32 for the {a,b}-gate pair. IEEE fma per half ->
// bit-exact vs two fmaf.
__device__ __forceinline__ floatx2 fma2(float s, floatx2 w, floatx2 acc) {
    return __builtin_elementwise_fma((floatx2){s, s}, w, acc);
}

// ---------------------------------------------------------------------------
// Kernel 1: LSTM scan — R21 = R19 structure (1 batch/block, 2 waves,
// 1 barrier/chunk; R20's 2-batch interleave stretched the step 600->990 cyc
// and is reverted) + two deltas:
//  (a) pk_fma: ga/gb gate dots as ONE float2 chain -> v_pk_fma_f32 halves the
//      dot FMA issue (64 fma -> 32 pk_fma per step). Bit-exact per half.
//  (b) cvt fused into the PRODUCER's slack (~2800 cyc/chunk): consumer drops
//      h into an LDS h-ring (1 predicated ds_write/step, off-chain); producer
//      converts the previous chunk to hh/hl (row) + th/tl (transposed) and
//      stores them. k_cvt kernel deleted. (R17: cvt in CONSUMER = +39 µs —
//      this puts it in the producer instead.)
// Queue fused as blk 64 (wave0 only), unchanged.
// ---------------------------------------------------------------------------
#define UU 8
__global__
__attribute__((amdgpu_flat_work_group_size(128, 128)))
__attribute__((amdgpu_waves_per_eu(1, 1)))
void k_lstm_scan(const int* __restrict__ ids,
                 const float* __restrict__ emb,
                 const float* __restrict__ klstm,
                 const float* __restrict__ bias,
                 const float* __restrict__ rk,
                 float* __restrict__ hout,
                 u16* __restrict__ hh, u16* __restrict__ hl,
                 u16* __restrict__ th, u16* __restrict__ tl,
                 int* __restrict__ list,
                 float* __restrict__ outq) {
    const int b = blockIdx.x;
    const int tid = threadIdx.x;
    const int wv = tid >> 6;   // wave 0 consumer / wave 1 producer+cvt
    const int l = tid & 63;
    if (b >= BB) {
        if (wv != 0) return;
        // ---- fused zero-index queue (single wave, no barriers) ----
        const int4* v4 = (const int4*)ids;
        const int C4 = (BB * TT) / 4 / 64;
        const int b4 = l * C4;
        int cnt = 0;
#pragma unroll 4
        for (int i = 0; i < C4; ++i) {
            int4 v = v4[b4 + i];
            cnt += (v.x == 0 || (unsigned)v.x >= VOCABN);
            cnt += (v.y == 0 || (unsigned)v.y >= VOCABN);
            cnt += (v.z == 0 || (unsigned)v.z >= VOCABN);
            cnt += (v.w == 0 || (unsigned)v.w >= VOCABN);
        }
        int scan = cnt;
#pragma unroll
        for (int o = 1; o < 64; o <<= 1) {
            int nn = __shfl_up(scan, o);
            if (l >= o) scan += nn;
        }
        const int total = __shfl(scan, 63);
        int off = scan - cnt;
        const int base = l * (C4 * 4);
#pragma unroll 4
        for (int i = 0; i < C4; ++i) {
            int4 v = v4[b4 + i];
            if (v.x == 0 || (unsigned)v.x >= VOCABN) list[off++] = base + 4 * i;
            if (v.y == 0 || (unsigned)v.y >= VOCABN) list[off++] = base + 4 * i + 1;
            if (v.z == 0 || (unsigned)v.z >= VOCABN) list[off++] = base + 4 * i + 2;
            if (v.w == 0 || (unsigned)v.w >= VOCABN) list[off++] = base + 4 * i + 3;
        }
        __threadfence();
        const int Kc = total < QLEN ? total : QLEN;
        for (int t = l; t < QLEN; t += 64) {
            float ii = -1.0f, jj = -1.0f;
            if (t >= QLEN - Kc) {
                int pos = list[total - QLEN + t];
                ii = (float)(pos >> 10);
                jj = (float)(pos & (TT - 1));
            }
            outq[2 * t] = ii;
            outq[2 * t + 1] = jj;
        }
        return;
    }

    __shared__ float ring[2][UU][GG];                    // 8 KB xg ring
    __shared__ __align__(16) float hring[2][UU][DD];     // 2 KB h ring (cvt)
    const int* idsb = ids + b * TT;

    if (wv == 1) {
        // ---------- producer: xg 8 tokens ahead + cvt of chunk-1 -----------
        const int ja = l, jb = l + 64;
        floatx2 kp[DD];
#pragma unroll
        for (int d2 = 0; d2 < DD; ++d2)
            kp[d2] = (floatx2){klstm[d2 * GG + ja], klstm[d2 * GG + jb]};
        const floatx2 bj = (floatx2){bias[ja], bias[jb]};
        const int dd = l & 31;
        // cvt lane mappings
        const int u_r = l >> 3, dc = (l & 7) * 4;        // row side: 8B u16 runs
        const int d_c = l & 31, ug = (l >> 5) * 4;       // col side: 4 consecutive t
        u16* hhb = hh + (size_t)b * TT * DD;
        u16* hlb = hl + (size_t)b * TT * DD;
        u16* thb = th + (size_t)b * DD * TT;
        u16* tlb = tl + (size_t)b * DD * TT;

#define PROD_TOKEN(SEL, U, EV)                                               \
        {                                                                    \
            floatx2 z0 = bj;                                                 \
            floatx2 z1 = {0.f, 0.f}, z2 = {0.f, 0.f}, z3 = {0.f, 0.f};       \
            _Pragma("unroll")                                                \
            for (int k = 0; k < DD; k += 4) {                                \
                float e0 = readlane_f(EV, k);                                \
                float e1 = readlane_f(EV, k + 1);                            \
                float e2 = readlane_f(EV, k + 2);                            \
                float e3 = readlane_f(EV, k + 3);                            \
                z0 = fma2(e0, kp[k], z0);                                    \
                z1 = fma2(e1, kp[k + 1], z1);                                \
                z2 = fma2(e2, kp[k + 2], z2);                                \
                z3 = fma2(e3, kp[k + 3], z3);                                \
            }                                                                \
            floatx2 zf = (z0 + z1) + (z2 + z3);                              \
            ring[SEL][U][ja] = zf.x;                                         \
            ring[SEL][U][jb] = zf.y;                                         \
        }

        // convert chunk starting at token TC0 from hring[HSEL]
#define CVT_CHUNK(HSEL, TC0)                                                 \
        {                                                                    \
            const float4 hv4 = *(const float4*)&hring[HSEL][u_r][dc];        \
            float xr[4] = {hv4.x, hv4.y, hv4.z, hv4.w};                      \
            u16 rh[4], rl[4];                                                \
            _Pragma("unroll")                                                \
            for (int i = 0; i < 4; ++i) {                                    \
                rh[i] = f2bf_rne(xr[i]);                                     \
                rl[i] = f2bf_rne(xr[i] - bf2f(rh[i]));                       \
            }                                                                \
            ushort4 rhv = {rh[0], rh[1], rh[2], rh[3]};                      \
            ushort4 rlv = {rl[0], rl[1], rl[2], rl[3]};                      \
            *(ushort4*)&hhb[(size_t)((TC0) + u_r) * DD + dc] = rhv;          \
            *(ushort4*)&hlb[(size_t)((TC0) + u_r) * DD + dc] = rlv;          \
            u16 ch[4], cl[4];                                                \
            _Pragma("unroll")                                                \
            for (int j = 0; j < 4; ++j) {                                    \
                float x = hring[HSEL][ug + j][d_c];                          \
                ch[j] = f2bf_rne(x);                                         \
                cl[j] = f2bf_rne(x - bf2f(ch[j]));                           \
            }                                                                \
            ushort4 chv = {ch[0], ch[1], ch[2], ch[3]};                      \
            ushort4 clv = {cl[0], cl[1], cl[2], cl[3]};                      \
            *(ushort4*)&thb[(size_t)d_c * TT + (TC0) + ug] = chv;            \
            *(ushort4*)&tlb[(size_t)d_c * TT + (TC0) + ug] = clv;            \
        }

        {
            int id0 = idsb[0]; if ((unsigned)id0 >= VOCABN) id0 = 0;
            float ec = emb[id0 * DD + dd];
#pragma unroll
            for (int u = 0; u < UU; ++u) {
                float en = 0.f;
                if (u + 1 < UU) {
                    int idn = idsb[u + 1]; if ((unsigned)idn >= VOCABN) idn = 0;
                    en = emb[idn * DD + dd];
                }
                PROD_TOKEN(0, u, ec)
                ec = en;
            }
        }
        __syncthreads();
        int sel = 0;
        for (int t0 = 0; t0 < TT; t0 += UU) {
            if (t0 + UU < TT) {
                const int s = sel ^ 1;
                int id0 = idsb[t0 + UU]; if ((unsigned)id0 >= VOCABN) id0 = 0;
                float ec = emb[id0 * DD + dd];
#pragma unroll
                for (int u = 0; u < UU; ++u) {
                    float en = 0.f;
                    if (u + 1 < UU) {
                        int tn = t0 + UU + u + 1;
                        if (tn > TT - 1) tn = TT - 1;
                        int idn = idsb[tn]; if ((unsigned)idn >= VOCABN) idn = 0;
                        en = emb[idn * DD + dd];
                    }
                    PROD_TOKEN(s, u, ec)
                    ec = en;
                }
            }
            // cvt previous chunk (consumer wrote hring[sel^1... parity of
            // chunk t0/UU-1] before the last barrier)
            if (t0) CVT_CHUNK((t0 / UU - 1) & 1, t0 - UU)
            __syncthreads();
            sel ^= 1;
        }
        // epilogue: convert the final chunk (written before the last barrier)
        CVT_CHUNK(1, TT - UU)
#undef PROD_TOKEN
#undef CVT_CHUNK
        return;
    }

    // ---------------- consumer: R19-exact scan + pk_fma dots ----------------
    const int d = l & 31;
    const bool hi = l >= 32;
    const int ga = (hi ? 32 : 0) + d;
    const int gb = (hi ? 96 : 64) + d;
    floatx2 rkp[DD];
#pragma unroll
    for (int k = 0; k < DD; ++k)
        rkp[k] = (floatx2){rk[k * GG + ga], rk[k * GG + gb]};
    float* hb = hout + (size_t)b * TT * DD;

    float h = 0.0f, c = 0.0f;
    float hreg[UU];
    __syncthreads();   // matches producer prologue barrier
    int sel = 0;
    for (int t0 = 0; t0 < TT; t0 += UU) {
        // flush previous chunk's h first: stores retire under this chunk's
        // compute, so the chunk-end barrier's vmcnt(0) drain is free.
        if (t0 && !hi) {
#pragma unroll
            for (int u = 0; u < UU; ++u) hb[(size_t)(t0 - UU + u) * DD + d] = hreg[u];
        }
        float pa[UU], pb[UU];
#pragma unroll
        for (int u = 0; u < UU; ++u) {
            pa[u] = ring[sel][u][ga];
            pb[u] = ring[sel][u][gb];
        }
#pragma unroll
        for (int u = 0; u < UU; ++u) {
            floatx2 x0 = {pa[u], pb[u]};
            floatx2 x1 = {0.f, 0.f}, x2 = {0.f, 0.f}, x3 = {0.f, 0.f};
#pragma unroll
            for (int k = 0; k < DD; k += 4) {
                float h0 = readlane_f(h, k);
                float h1 = readlane_f(h, k + 1);
                float h2 = readlane_f(h, k + 2);
                float h3 = readlane_f(h, k + 3);
                x0 = fma2(h0, rkp[k],     x0);
                x1 = fma2(h1, rkp[k + 1], x1);
                x2 = fma2(h2, rkp[k + 2], x2);
                x3 = fma2(h3, rkp[k + 3], x3);
            }
            floatx2 zf = (x0 + x1) + (x2 + x3);
            float za = zf.x, zb = zf.y;
            float a = fsig(za);                       // sig(i) lo / sig(f) hi
            float zbm = hi ? zb : 2.0f * zb;
            float s2 = fsig(zbm);
            float bv = hi ? s2 : 2.0f * s2 - 1.0f;    // sig(o) hi / tanh(g) lo
            // lane<32 <-> lane+32 exchange via v_permlane32_swap_b32 (VALU).
            auto r1 = __builtin_amdgcn_permlane32_swap(
                __float_as_int(bv), __float_as_int(a), false, false);
            auto r2 = __builtin_amdgcn_permlane32_swap(
                __float_as_int(a), __float_as_int(bv), false, false);
            float fg = __int_as_float(r1[0]);
            float og = __int_as_float(r2[0]);
            c = fmaf(fg, c, a * bv);
            float tc = 2.0f * fsig(2.0f * c) - 1.0f;
            h = og * tc;
            hreg[u] = h;
            if (!hi) hring[sel][u][d] = h;   // h ring for producer-side cvt
        }
        __syncthreads();
        sel ^= 1;
    }
    if (!hi) {
#pragma unroll
        for (int u = 0; u < UU; ++u) hb[(size_t)(TT - UU + u) * DD + d] = hreg[u];
    }
}

// ---------------------------------------------------------------------------
// Kernel 3: attention on MFMA — R16 P-lag version (absmax 0.0, measured).
// ---------------------------------------------------------------------------
__global__ __launch_bounds__(256, 4) void k_attn(const u16* __restrict__ hh,
                                                 const u16* __restrict__ hl,
                                                 const u16* __restrict__ th,
                                                 const u16* __restrict__ tl,
                                                 float* __restrict__ ctx) {
    __shared__ u16 plds[4][2][16 * 40];   // per-wave double-buffered P
    const int tid = threadIdx.x;
    const int w = tid >> 6;
    const int l = tid & 63;
    const int m = l & 15;
    const int g = l >> 4;
    const int b = blockIdx.x & 63;              // XCD swizzle: XCD = b % 8
    const int qt = (blockIdx.x >> 6) * 4 + w;
    const int q0 = qt * 16;
    const size_t rb = (size_t)b * TT * DD;
    const size_t tb = (size_t)b * DD * TT;

    const short8 Qh = *(const short8*)&hh[rb + (size_t)(q0 + m) * DD + g * 8];
    const short8 Ql = *(const short8*)&hl[rb + (size_t)(q0 + m) * DD + g * 8];
    short8 ONES;
#pragma unroll
    for (int j = 0; j < 8; ++j) ONES[j] = (short)0x3F80;

    floatx4 c0 = {0.f, 0.f, 0.f, 0.f};
    floatx4 c1 = {0.f, 0.f, 0.f, 0.f};
    floatx4 la = {0.f, 0.f, 0.f, 0.f};

#define S_BLOCK(KH_A, KL_A, KH_B, KL_B, SA, SB)                               \
    SA = __builtin_amdgcn_mfma_f32_16x16x32_bf16(Qh, KH_A, SA, 0, 0, 0);      \
    SA = __builtin_amdgcn_mfma_f32_16x16x32_bf16(Qh, KL_A, SA, 0, 0, 0);      \
    SA = __builtin_amdgcn_mfma_f32_16x16x32_bf16(Ql, KH_A, SA, 0, 0, 0);      \
    SB = __builtin_amdgcn_mfma_f32_16x16x32_bf16(Qh, KH_B, SB, 0, 0, 0);      \
    SB = __builtin_amdgcn_mfma_f32_16x16x32_bf16(Qh, KL_B, SB, 0, 0, 0);      \
    SB = __builtin_amdgcn_mfma_f32_16x16x32_bf16(Ql, KH_B, SB, 0, 0, 0);

    // ---- kp = 0: S + exp + write slot0; no PV yet ----
    {
        short8 KhA = *(const short8*)&hh[rb + (size_t)(m) * DD + g * 8];
        short8 KlA = *(const short8*)&hl[rb + (size_t)(m) * DD + g * 8];
        short8 KhB = *(const short8*)&hh[rb + (size_t)(16 + m) * DD + g * 8];
        short8 KlB = *(const short8*)&hl[rb + (size_t)(16 + m) * DD + g * 8];
        floatx4 sA = {0.f, 0.f, 0.f, 0.f};
        floatx4 sB = {0.f, 0.f, 0.f, 0.f};
        S_BLOCK(KhA, KlA, KhB, KlB, sA, sB)
        u16* lds0 = plds[w][0];
#pragma unroll
        for (int r = 0; r < 4; ++r) {
            lds0[(g * 4 + r) * 40 + m]      = f2bf_rne(__expf(sA[r]));
            lds0[(g * 4 + r) * 40 + 16 + m] = f2bf_rne(__expf(sB[r]));
        }
    }
    // preload V_0 (used at kp=1) and K_1
    short8 Vh0 = *(const short8*)&th[tb + (size_t)m * TT + g * 8];
    short8 Vl0 = *(const short8*)&tl[tb + (size_t)m * TT + g * 8];
    short8 Vh1 = *(const short8*)&th[tb + (size_t)(16 + m) * TT + g * 8];
    short8 Vl1 = *(const short8*)&tl[tb + (size_t)(16 + m) * TT + g * 8];
    short8 KhA = *(const short8*)&hh[rb + (size_t)(32 + m) * DD + g * 8];
    short8 KlA = *(const short8*)&hl[rb + (size_t)(32 + m) * DD + g * 8];
    short8 KhB = *(const short8*)&hh[rb + (size_t)(48 + m) * DD + g * 8];
    short8 KlB = *(const short8*)&hl[rb + (size_t)(48 + m) * DD + g * 8];

#pragma unroll 1
    for (int kp = 1; kp < 32; ++kp) {
        const int knK = (kp < 31) ? (kp + 1) * 32 : 0;
        const int knV = kp * 32;
        short8 nKhA = *(const short8*)&hh[rb + (size_t)(knK + m) * DD + g * 8];
        short8 nKlA = *(const short8*)&hl[rb + (size_t)(knK + m) * DD + g * 8];
        short8 nKhB = *(const short8*)&hh[rb + (size_t)(knK + 16 + m) * DD + g * 8];
        short8 nKlB = *(const short8*)&hl[rb + (size_t)(knK + 16 + m) * DD + g * 8];
        short8 nVh0 = *(const short8*)&th[tb + (size_t)m * TT + knV + g * 8];
        short8 nVl0 = *(const short8*)&tl[tb + (size_t)m * TT + knV + g * 8];
        short8 nVh1 = *(const short8*)&th[tb + (size_t)(16 + m) * TT + knV + g * 8];
        short8 nVl1 = *(const short8*)&tl[tb + (size_t)(16 + m) * TT + knV + g * 8];

        floatx4 sA = {0.f, 0.f, 0.f, 0.f};
        floatx4 sB = {0.f, 0.f, 0.f, 0.f};
        S_BLOCK(KhA, KlA, KhB, KlB, sA, sB)

        const short8 P = *(const short8*)&plds[w][(kp - 1) & 1][m * 40 + g * 8];

        u16 pe[8];
#pragma unroll
        for (int r = 0; r < 4; ++r) {
            pe[r]     = f2bf_rne(__expf(sA[r]));
            pe[4 + r] = f2bf_rne(__expf(sB[r]));
        }

        c0 = __builtin_amdgcn_mfma_f32_16x16x32_bf16(P, Vh0, c0, 0, 0, 0);
        c0 = __builtin_amdgcn_mfma_f32_16x16x32_bf16(P, Vl0, c0, 0, 0, 0);
        c1 = __builtin_amdgcn_mfma_f32_16x16x32_bf16(P, Vh1, c1, 0, 0, 0);
        c1 = __builtin_amdgcn_mfma_f32_16x16x32_bf16(P, Vl1, c1, 0, 0, 0);
        la = __builtin_amdgcn_mfma_f32_16x16x32_bf16(P, ONES, la, 0, 0, 0);

        u16* lds = plds[w][kp & 1];
#pragma unroll
        for (int r = 0; r < 4; ++r) {
            lds[(g * 4 + r) * 40 + m]      = pe[r];
            lds[(g * 4 + r) * 40 + 16 + m] = pe[4 + r];
        }

        KhA = nKhA; KlA = nKlA; KhB = nKhB; KlB = nKlB;
        Vh0 = nVh0; Vl0 = nVl0; Vh1 = nVh1; Vl1 = nVl1;
    }
    // epilogue: PV of kp=31
    {
        const short8 P = *(const short8*)&plds[w][31 & 1][m * 40 + g * 8];
        c0 = __builtin_amdgcn_mfma_f32_16x16x32_bf16(P, Vh0, c0, 0, 0, 0);
        c0 = __builtin_amdgcn_mfma_f32_16x16x32_bf16(P, Vl0, c0, 0, 0, 0);
        c1 = __builtin_amdgcn_mfma_f32_16x16x32_bf16(P, Vh1, c1, 0, 0, 0);
        c1 = __builtin_amdgcn_mfma_f32_16x16x32_bf16(P, Vl1, c1, 0, 0, 0);
        la = __builtin_amdgcn_mfma_f32_16x16x32_bf16(P, ONES, la, 0, 0, 0);
    }
#undef S_BLOCK
#pragma unroll
    for (int r = 0; r < 4; ++r) {
        float linv = __builtin_amdgcn_rcpf(la[r]);
        float* crow = ctx + (size_t)b * TT * DD + (size_t)(q0 + g * 4 + r) * DD;
        crow[m]      = c0[r] * linv;
        crow[16 + m] = c1[r] * linv;
    }
}

// ---------------------------------------------------------------------------
// Kernel 4: ymlp — R13 version, unchanged.
// ---------------------------------------------------------------------------
__global__ __launch_bounds__(256) void k_ymlp(const float* __restrict__ ctx,
                                              const float* __restrict__ h,
                                              const float* __restrict__ W1,
                                              const float* __restrict__ b1,
                                              const float* __restrict__ W2,
                                              const float* __restrict__ b2,
                                              float* __restrict__ out) {
    const int b = blockIdx.x;
    const int tid = threadIdx.x;
    __shared__ __align__(16) float cs[128 * DD];
    __shared__ __align__(16) float hs[128 * DD];
    const float* cb = ctx + (size_t)b * TT * DD;
    const float* hb = h + (size_t)b * TT * DD;
    const int e = tid & 31;
    const int d4 = (tid >> 5) * 4;
    float acc[4] = {0.f, 0.f, 0.f, 0.f};
    for (int kt = 0; kt < 8; ++kt) {
        const float4* s1 = (const float4*)(cb + (size_t)kt * 128 * DD);
        const float4* s2 = (const float4*)(hb + (size_t)kt * 128 * DD);
        float4* t1 = (float4*)cs;
        float4* t2 = (float4*)hs;
#pragma unroll
        for (int n = 0; n < 4; ++n) {
            t1[tid + n * 256] = s1[tid + n * 256];
            t2[tid + n * 256] = s2[tid + n * 256];
        }
        __syncthreads();
#pragma unroll 2
        for (int s = 0; s < 128; ++s) {
            float hv = hs[s * DD + e];
            float4 cv = *(const float4*)&cs[s * DD + d4];
            acc[0] = fmaf(cv.x, hv, acc[0]);
            acc[1] = fmaf(cv.y, hv, acc[1]);
            acc[2] = fmaf(cv.z, hv, acc[2]);
            acc[3] = fmaf(cv.w, hv, acc[3]);
        }
        __syncthreads();
    }
    __shared__ float ys[DD][DD];
#pragma unroll
    for (int r = 0; r < 4; ++r) ys[d4 + r][e] = acc[r];
    __syncthreads();
    __shared__ float yr[DD][33];
#pragma unroll
    for (int r = 0; r < 4; ++r) {
        float v = b1[e];
#pragma unroll
        for (int ee = 0; ee < DD; ++ee) v += ys[d4 + r][ee] * W1[ee * DD + e];
        yr[d4 + r][e] = fmaxf(v, 0.0f);
    }
    __syncthreads();
    if (tid < DD) {
        float v = b2[0];
#pragma unroll
        for (int ee = 0; ee < DD; ++ee) v += yr[tid][ee] * W2[ee];
        out[b * DD + tid] = 1.0f / (1.0f + expf(-v));
    }
}

// ---------------------------------------------------------------------------
extern "C" void kernel_launch(void* const* d_in, const int* in_sizes, int n_in,
                              void* d_out, int out_size, void* d_ws, size_t ws_size,
                              hipStream_t stream) {
    const int* ids   = (const int*)d_in[0];
    const float* emb = (const float*)d_in[1];
    const float* kl  = (const float*)d_in[2];
    const float* rk  = (const float*)d_in[3];
    const float* bl  = (const float*)d_in[4];
    const float* W1  = (const float*)d_in[5];
    const float* b1  = (const float*)d_in[6];
    const float* W2  = (const float*)d_in[7];
    const float* b2  = (const float*)d_in[8];
    float* out = (float*)d_out;

    char* ws = (char*)d_ws;
    const size_t H_ELEMS = (size_t)BB * TT * DD;   // 2,097,152
    u16* hh   = (u16*)ws;
    u16* hl   = (u16*)(ws + H_ELEMS * 2);
    u16* th   = (u16*)(ws + H_ELEMS * 4);
    u16* tl   = (u16*)(ws + H_ELEMS * 6);
    float* h  = (float*)(ws + H_ELEMS * 8);
    float* ctx = (float*)(ws + H_ELEMS * 8 + H_ELEMS * 4);
    int* list = (int*)(ws + H_ELEMS * 8 + H_ELEMS * 8);

    k_lstm_scan<<<BB + 1, 128, 0, stream>>>(ids, emb, kl, bl, rk, h,
                                            hh, hl, th, tl, list, out + BB * DD);
    k_attn<<<BB * 16, 256, 0, stream>>>(hh, hl, th, tl, ctx);
    k_ymlp<<<BB, 256, 0, stream>>>(ctx, h, W1, b1, W2, b2, out);
}

// Round 5
// 390.451 us; speedup vs baseline: 1.5839x; 1.1048x over previous
//
#include <hip/hip_runtime.h>
#include <math.h>

#define BB 64
#define TT 1024
#define DD 32
#define GG 128   // 4*D
#define VOCABN 10000
#define QLEN 100

typedef short short8 __attribute__((ext_vector_type(8)));   // 8 bf16 in 4 VGPRs
typedef float floatx4 __attribute__((ext_vector_type(4)));
typedef float floatx2 __attribute__((ext_vector_type(2)));
typedef unsigned short u16;

__device__ __forceinline__ float fsig(float x) {
    return __builtin_amdgcn_rcpf(1.0f + __expf(-x));
}
__device__ __forceinline__ float readlane_f(float v, int l) {
    return __int_as_float(__builtin_amdgcn_readlane(__float_as_int(v), l));
}
__device__ __forceinline__ u16 f2bf_rne(float x) {
    unsigned u = __float_as_uint(x);
    u += 0x7FFF + ((u >> 16) & 1);
    return (u16)(u >> 16);
}
__device__ __forceinline__ float bf2f(u16 s) {
    return __uint_as_float(((unsigned)s) << 16);
}
// packed fma: one v_pk_fma_f32 for the {a,b}-gate pair. IEEE fma per half ->
// bit-exact vs two fmaf.
__device__ __forceinline__ floatx2 fma2(float s, floatx2 w, floatx2 acc) {
    return __builtin_elementwise_fma((floatx2){s, s}, w, acc);
}

// ---------------------------------------------------------------------------
// Kernel 1: LSTM scan — R21 version (measured 241 µs), UNCHANGED.
// R19 structure + pk_fma dots + cvt fused into producer slack.
// ---------------------------------------------------------------------------
#define UU 8
__global__
__attribute__((amdgpu_flat_work_group_size(128, 128)))
__attribute__((amdgpu_waves_per_eu(1, 1)))
void k_lstm_scan(const int* __restrict__ ids,
                 const float* __restrict__ emb,
                 const float* __restrict__ klstm,
                 const float* __restrict__ bias,
                 const float* __restrict__ rk,
                 float* __restrict__ hout,
                 u16* __restrict__ hh, u16* __restrict__ hl,
                 u16* __restrict__ th, u16* __restrict__ tl,
                 int* __restrict__ list,
                 float* __restrict__ outq) {
    const int b = blockIdx.x;
    const int tid = threadIdx.x;
    const int wv = tid >> 6;   // wave 0 consumer / wave 1 producer+cvt
    const int l = tid & 63;
    if (b >= BB) {
        if (wv != 0) return;
        // ---- fused zero-index queue (single wave, no barriers) ----
        const int4* v4 = (const int4*)ids;
        const int C4 = (BB * TT) / 4 / 64;
        const int b4 = l * C4;
        int cnt = 0;
#pragma unroll 4
        for (int i = 0; i < C4; ++i) {
            int4 v = v4[b4 + i];
            cnt += (v.x == 0 || (unsigned)v.x >= VOCABN);
            cnt += (v.y == 0 || (unsigned)v.y >= VOCABN);
            cnt += (v.z == 0 || (unsigned)v.z >= VOCABN);
            cnt += (v.w == 0 || (unsigned)v.w >= VOCABN);
        }
        int scan = cnt;
#pragma unroll
        for (int o = 1; o < 64; o <<= 1) {
            int nn = __shfl_up(scan, o);
            if (l >= o) scan += nn;
        }
        const int total = __shfl(scan, 63);
        int off = scan - cnt;
        const int base = l * (C4 * 4);
#pragma unroll 4
        for (int i = 0; i < C4; ++i) {
            int4 v = v4[b4 + i];
            if (v.x == 0 || (unsigned)v.x >= VOCABN) list[off++] = base + 4 * i;
            if (v.y == 0 || (unsigned)v.y >= VOCABN) list[off++] = base + 4 * i + 1;
            if (v.z == 0 || (unsigned)v.z >= VOCABN) list[off++] = base + 4 * i + 2;
            if (v.w == 0 || (unsigned)v.w >= VOCABN) list[off++] = base + 4 * i + 3;
        }
        __threadfence();
        const int Kc = total < QLEN ? total : QLEN;
        for (int t = l; t < QLEN; t += 64) {
            float ii = -1.0f, jj = -1.0f;
            if (t >= QLEN - Kc) {
                int pos = list[total - QLEN + t];
                ii = (float)(pos >> 10);
                jj = (float)(pos & (TT - 1));
            }
            outq[2 * t] = ii;
            outq[2 * t + 1] = jj;
        }
        return;
    }

    __shared__ float ring[2][UU][GG];                    // 8 KB xg ring
    __shared__ __align__(16) float hring[2][UU][DD];     // 2 KB h ring (cvt)
    const int* idsb = ids + b * TT;

    if (wv == 1) {
        // ---------- producer: xg 8 tokens ahead + cvt of chunk-1 -----------
        const int ja = l, jb = l + 64;
        floatx2 kp[DD];
#pragma unroll
        for (int d2 = 0; d2 < DD; ++d2)
            kp[d2] = (floatx2){klstm[d2 * GG + ja], klstm[d2 * GG + jb]};
        const floatx2 bj = (floatx2){bias[ja], bias[jb]};
        const int dd = l & 31;
        // cvt lane mappings
        const int u_r = l >> 3, dc = (l & 7) * 4;        // row side: 8B u16 runs
        const int d_c = l & 31, ug = (l >> 5) * 4;       // col side: 4 consecutive t
        u16* hhb = hh + (size_t)b * TT * DD;
        u16* hlb = hl + (size_t)b * TT * DD;
        u16* thb = th + (size_t)b * DD * TT;
        u16* tlb = tl + (size_t)b * DD * TT;

#define PROD_TOKEN(SEL, U, EV)                                               \
        {                                                                    \
            floatx2 z0 = bj;                                                 \
            floatx2 z1 = {0.f, 0.f}, z2 = {0.f, 0.f}, z3 = {0.f, 0.f};       \
            _Pragma("unroll")                                                \
            for (int k = 0; k < DD; k += 4) {                                \
                float e0 = readlane_f(EV, k);                                \
                float e1 = readlane_f(EV, k + 1);                            \
                float e2 = readlane_f(EV, k + 2);                            \
                float e3 = readlane_f(EV, k + 3);                            \
                z0 = fma2(e0, kp[k], z0);                                    \
                z1 = fma2(e1, kp[k + 1], z1);                                \
                z2 = fma2(e2, kp[k + 2], z2);                                \
                z3 = fma2(e3, kp[k + 3], z3);                                \
            }                                                                \
            floatx2 zf = (z0 + z1) + (z2 + z3);                              \
            ring[SEL][U][ja] = zf.x;                                         \
            ring[SEL][U][jb] = zf.y;                                         \
        }

        // convert chunk starting at token TC0 from hring[HSEL]
#define CVT_CHUNK(HSEL, TC0)                                                 \
        {                                                                    \
            const float4 hv4 = *(const float4*)&hring[HSEL][u_r][dc];        \
            float xr[4] = {hv4.x, hv4.y, hv4.z, hv4.w};                      \
            u16 rh[4], rl[4];                                                \
            _Pragma("unroll")                                                \
            for (int i = 0; i < 4; ++i) {                                    \
                rh[i] = f2bf_rne(xr[i]);                                     \
                rl[i] = f2bf_rne(xr[i] - bf2f(rh[i]));                       \
            }                                                                \
            ushort4 rhv = {rh[0], rh[1], rh[2], rh[3]};                      \
            ushort4 rlv = {rl[0], rl[1], rl[2], rl[3]};                      \
            *(ushort4*)&hhb[(size_t)((TC0) + u_r) * DD + dc] = rhv;          \
            *(ushort4*)&hlb[(size_t)((TC0) + u_r) * DD + dc] = rlv;          \
            u16 ch[4], cl[4];                                                \
            _Pragma("unroll")                                                \
            for (int j = 0; j < 4; ++j) {                                    \
                float x = hring[HSEL][ug + j][d_c];                          \
                ch[j] = f2bf_rne(x);                                         \
                cl[j] = f2bf_rne(x - bf2f(ch[j]));                           \
            }                                                                \
            ushort4 chv = {ch[0], ch[1], ch[2], ch[3]};                      \
            ushort4 clv = {cl[0], cl[1], cl[2], cl[3]};                      \
            *(ushort4*)&thb[(size_t)d_c * TT + (TC0) + ug] = chv;            \
            *(ushort4*)&tlb[(size_t)d_c * TT + (TC0) + ug] = clv;            \
        }

        {
            int id0 = idsb[0]; if ((unsigned)id0 >= VOCABN) id0 = 0;
            float ec = emb[id0 * DD + dd];
#pragma unroll
            for (int u = 0; u < UU; ++u) {
                float en = 0.f;
                if (u + 1 < UU) {
                    int idn = idsb[u + 1]; if ((unsigned)idn >= VOCABN) idn = 0;
                    en = emb[idn * DD + dd];
                }
                PROD_TOKEN(0, u, ec)
                ec = en;
            }
        }
        __syncthreads();
        int sel = 0;
        for (int t0 = 0; t0 < TT; t0 += UU) {
            if (t0 + UU < TT) {
                const int s = sel ^ 1;
                int id0 = idsb[t0 + UU]; if ((unsigned)id0 >= VOCABN) id0 = 0;
                float ec = emb[id0 * DD + dd];
#pragma unroll
                for (int u = 0; u < UU; ++u) {
                    float en = 0.f;
                    if (u + 1 < UU) {
                        int tn = t0 + UU + u + 1;
                        if (tn > TT - 1) tn = TT - 1;
                        int idn = idsb[tn]; if ((unsigned)idn >= VOCABN) idn = 0;
                        en = emb[idn * DD + dd];
                    }
                    PROD_TOKEN(s, u, ec)
                    ec = en;
                }
            }
            // cvt previous chunk (consumer wrote hring[(t0/UU-1)&1] before
            // the last barrier)
            if (t0) CVT_CHUNK((t0 / UU - 1) & 1, t0 - UU)
            __syncthreads();
            sel ^= 1;
        }
        // epilogue: convert the final chunk (written before the last barrier)
        CVT_CHUNK(1, TT - UU)
#undef PROD_TOKEN
#undef CVT_CHUNK
        return;
    }

    // ---------------- consumer: R19-exact scan + pk_fma dots ----------------
    const int d = l & 31;
    const bool hi = l >= 32;
    const int ga = (hi ? 32 : 0) + d;
    const int gb = (hi ? 96 : 64) + d;
    floatx2 rkp[DD];
#pragma unroll
    for (int k = 0; k < DD; ++k)
        rkp[k] = (floatx2){rk[k * GG + ga], rk[k * GG + gb]};
    float* hb = hout + (size_t)b * TT * DD;

    float h = 0.0f, c = 0.0f;
    float hreg[UU];
    __syncthreads();   // matches producer prologue barrier
    int sel = 0;
    for (int t0 = 0; t0 < TT; t0 += UU) {
        // flush previous chunk's h first: stores retire under this chunk's
        // compute, so the chunk-end barrier's vmcnt(0) drain is free.
        if (t0 && !hi) {
#pragma unroll
            for (int u = 0; u < UU; ++u) hb[(size_t)(t0 - UU + u) * DD + d] = hreg[u];
        }
        float pa[UU], pb[UU];
#pragma unroll
        for (int u = 0; u < UU; ++u) {
            pa[u] = ring[sel][u][ga];
            pb[u] = ring[sel][u][gb];
        }
#pragma unroll
        for (int u = 0; u < UU; ++u) {
            floatx2 x0 = {pa[u], pb[u]};
            floatx2 x1 = {0.f, 0.f}, x2 = {0.f, 0.f}, x3 = {0.f, 0.f};
#pragma unroll
            for (int k = 0; k < DD; k += 4) {
                float h0 = readlane_f(h, k);
                float h1 = readlane_f(h, k + 1);
                float h2 = readlane_f(h, k + 2);
                float h3 = readlane_f(h, k + 3);
                x0 = fma2(h0, rkp[k],     x0);
                x1 = fma2(h1, rkp[k + 1], x1);
                x2 = fma2(h2, rkp[k + 2], x2);
                x3 = fma2(h3, rkp[k + 3], x3);
            }
            floatx2 zf = (x0 + x1) + (x2 + x3);
            float za = zf.x, zb = zf.y;
            float a = fsig(za);                       // sig(i) lo / sig(f) hi
            float zbm = hi ? zb : 2.0f * zb;
            float s2 = fsig(zbm);
            float bv = hi ? s2 : 2.0f * s2 - 1.0f;    // sig(o) hi / tanh(g) lo
            // lane<32 <-> lane+32 exchange via v_permlane32_swap_b32 (VALU).
            auto r1 = __builtin_amdgcn_permlane32_swap(
                __float_as_int(bv), __float_as_int(a), false, false);
            auto r2 = __builtin_amdgcn_permlane32_swap(
                __float_as_int(a), __float_as_int(bv), false, false);
            float fg = __int_as_float(r1[0]);
            float og = __int_as_float(r2[0]);
            c = fmaf(fg, c, a * bv);
            float tc = 2.0f * fsig(2.0f * c) - 1.0f;
            h = og * tc;
            hreg[u] = h;
            if (!hi) hring[sel][u][d] = h;   // h ring for producer-side cvt
        }
        __syncthreads();
        sel ^= 1;
    }
    if (!hi) {
#pragma unroll
        for (int u = 0; u < UU; ++u) hb[(size_t)(TT - UU + u) * DD + d] = hreg[u];
    }
}

// ---------------------------------------------------------------------------
// Kernel 3: attention — R22: TWO q-tiles (32 q-rows) per wave. K/V loads and
// their registers are SHARED by both tiles: per iteration the same 8 16-B
// loads now feed 22 MFMAs (was 11) and 4 independent S-chains + 6 acc chains
// (was 2+3) -> 2x arithmetic intensity and 2x latency-hiding ILP, half the
// K/V traffic. Grid halves to BB*8 (2 blocks/CU). Per-tile math is op-for-op
// the R16 P-lag scheme (absmax 0.0 preserved).
// ---------------------------------------------------------------------------
__global__ __launch_bounds__(256, 2) void k_attn(const u16* __restrict__ hh,
                                                 const u16* __restrict__ hl,
                                                 const u16* __restrict__ th,
                                                 const u16* __restrict__ tl,
                                                 float* __restrict__ ctx) {
    __shared__ u16 plds[4][2][2][16 * 40];   // [wave][tile][dbuf][16x40]
    const int tid = threadIdx.x;
    const int w = tid >> 6;
    const int l = tid & 63;
    const int m = l & 15;
    const int g = l >> 4;
    const int b = blockIdx.x & 63;              // XCD swizzle: XCD = b % 8
    const int qt = (blockIdx.x >> 6) * 4 + w;   // 32-row wave tile, 0..31
    const int q0 = qt * 32;
    const size_t rb = (size_t)b * TT * DD;
    const size_t tb = (size_t)b * DD * TT;

    const short8 Qh0 = *(const short8*)&hh[rb + (size_t)(q0 + m) * DD + g * 8];
    const short8 Ql0 = *(const short8*)&hl[rb + (size_t)(q0 + m) * DD + g * 8];
    const short8 Qh1 = *(const short8*)&hh[rb + (size_t)(q0 + 16 + m) * DD + g * 8];
    const short8 Ql1 = *(const short8*)&hl[rb + (size_t)(q0 + 16 + m) * DD + g * 8];
    short8 ONES;
#pragma unroll
    for (int j = 0; j < 8; ++j) ONES[j] = (short)0x3F80;

    floatx4 c0 = {0.f, 0.f, 0.f, 0.f};   // tile0 cols 0-15
    floatx4 c1 = {0.f, 0.f, 0.f, 0.f};   // tile0 cols 16-31
    floatx4 c2 = {0.f, 0.f, 0.f, 0.f};   // tile1 cols 0-15
    floatx4 c3 = {0.f, 0.f, 0.f, 0.f};   // tile1 cols 16-31
    floatx4 la0 = {0.f, 0.f, 0.f, 0.f};
    floatx4 la1 = {0.f, 0.f, 0.f, 0.f};

#define S_BLOCK(QH, QL, KH_A, KL_A, KH_B, KL_B, SA, SB)                       \
    SA = __builtin_amdgcn_mfma_f32_16x16x32_bf16(QH, KH_A, SA, 0, 0, 0);      \
    SA = __builtin_amdgcn_mfma_f32_16x16x32_bf16(QH, KL_A, SA, 0, 0, 0);      \
    SA = __builtin_amdgcn_mfma_f32_16x16x32_bf16(QL, KH_A, SA, 0, 0, 0);      \
    SB = __builtin_amdgcn_mfma_f32_16x16x32_bf16(QH, KH_B, SB, 0, 0, 0);      \
    SB = __builtin_amdgcn_mfma_f32_16x16x32_bf16(QH, KL_B, SB, 0, 0, 0);      \
    SB = __builtin_amdgcn_mfma_f32_16x16x32_bf16(QL, KH_B, SB, 0, 0, 0);

    // ---- kp = 0: S + exp + write slot0 for BOTH tiles; no PV yet ----
    {
        short8 KhA = *(const short8*)&hh[rb + (size_t)(m) * DD + g * 8];
        short8 KlA = *(const short8*)&hl[rb + (size_t)(m) * DD + g * 8];
        short8 KhB = *(const short8*)&hh[rb + (size_t)(16 + m) * DD + g * 8];
        short8 KlB = *(const short8*)&hl[rb + (size_t)(16 + m) * DD + g * 8];
        floatx4 sA = {0.f, 0.f, 0.f, 0.f};
        floatx4 sB = {0.f, 0.f, 0.f, 0.f};
        floatx4 tA = {0.f, 0.f, 0.f, 0.f};
        floatx4 tB = {0.f, 0.f, 0.f, 0.f};
        S_BLOCK(Qh0, Ql0, KhA, KlA, KhB, KlB, sA, sB)
        S_BLOCK(Qh1, Ql1, KhA, KlA, KhB, KlB, tA, tB)
        u16* p0 = plds[w][0][0];
        u16* p1 = plds[w][1][0];
#pragma unroll
        for (int r = 0; r < 4; ++r) {
            p0[(g * 4 + r) * 40 + m]      = f2bf_rne(__expf(sA[r]));
            p0[(g * 4 + r) * 40 + 16 + m] = f2bf_rne(__expf(sB[r]));
            p1[(g * 4 + r) * 40 + m]      = f2bf_rne(__expf(tA[r]));
            p1[(g * 4 + r) * 40 + 16 + m] = f2bf_rne(__expf(tB[r]));
        }
    }
    // preload V_0 (used at kp=1) and K_1 — shared by both tiles
    short8 Vh0 = *(const short8*)&th[tb + (size_t)m * TT + g * 8];
    short8 Vl0 = *(const short8*)&tl[tb + (size_t)m * TT + g * 8];
    short8 Vh1 = *(const short8*)&th[tb + (size_t)(16 + m) * TT + g * 8];
    short8 Vl1 = *(const short8*)&tl[tb + (size_t)(16 + m) * TT + g * 8];
    short8 KhA = *(const short8*)&hh[rb + (size_t)(32 + m) * DD + g * 8];
    short8 KlA = *(const short8*)&hl[rb + (size_t)(32 + m) * DD + g * 8];
    short8 KhB = *(const short8*)&hh[rb + (size_t)(48 + m) * DD + g * 8];
    short8 KlB = *(const short8*)&hl[rb + (size_t)(48 + m) * DD + g * 8];

#pragma unroll 1
    for (int kp = 1; kp < 32; ++kp) {
        const int knK = (kp < 31) ? (kp + 1) * 32 : 0;
        const int knV = kp * 32;
        short8 nKhA = *(const short8*)&hh[rb + (size_t)(knK + m) * DD + g * 8];
        short8 nKlA = *(const short8*)&hl[rb + (size_t)(knK + m) * DD + g * 8];
        short8 nKhB = *(const short8*)&hh[rb + (size_t)(knK + 16 + m) * DD + g * 8];
        short8 nKlB = *(const short8*)&hl[rb + (size_t)(knK + 16 + m) * DD + g * 8];
        short8 nVh0 = *(const short8*)&th[tb + (size_t)m * TT + knV + g * 8];
        short8 nVl0 = *(const short8*)&tl[tb + (size_t)m * TT + knV + g * 8];
        short8 nVh1 = *(const short8*)&th[tb + (size_t)(16 + m) * TT + knV + g * 8];
        short8 nVl1 = *(const short8*)&tl[tb + (size_t)(16 + m) * TT + knV + g * 8];

        floatx4 sA = {0.f, 0.f, 0.f, 0.f};
        floatx4 sB = {0.f, 0.f, 0.f, 0.f};
        floatx4 tA = {0.f, 0.f, 0.f, 0.f};
        floatx4 tB = {0.f, 0.f, 0.f, 0.f};
        S_BLOCK(Qh0, Ql0, KhA, KlA, KhB, KlB, sA, sB)
        S_BLOCK(Qh1, Ql1, KhA, KlA, KhB, KlB, tA, tB)

        const short8 P0 = *(const short8*)&plds[w][0][(kp - 1) & 1][m * 40 + g * 8];
        const short8 P1 = *(const short8*)&plds[w][1][(kp - 1) & 1][m * 40 + g * 8];

        u16 pe0[8], pe1[8];
#pragma unroll
        for (int r = 0; r < 4; ++r) {
            pe0[r]     = f2bf_rne(__expf(sA[r]));
            pe0[4 + r] = f2bf_rne(__expf(sB[r]));
            pe1[r]     = f2bf_rne(__expf(tA[r]));
            pe1[4 + r] = f2bf_rne(__expf(tB[r]));
        }

        c0  = __builtin_amdgcn_mfma_f32_16x16x32_bf16(P0, Vh0, c0, 0, 0, 0);
        c0  = __builtin_amdgcn_mfma_f32_16x16x32_bf16(P0, Vl0, c0, 0, 0, 0);
        c1  = __builtin_amdgcn_mfma_f32_16x16x32_bf16(P0, Vh1, c1, 0, 0, 0);
        c1  = __builtin_amdgcn_mfma_f32_16x16x32_bf16(P0, Vl1, c1, 0, 0, 0);
        la0 = __builtin_amdgcn_mfma_f32_16x16x32_bf16(P0, ONES, la0, 0, 0, 0);
        c2  = __builtin_amdgcn_mfma_f32_16x16x32_bf16(P1, Vh0, c2, 0, 0, 0);
        c2  = __builtin_amdgcn_mfma_f32_16x16x32_bf16(P1, Vl0, c2, 0, 0, 0);
        c3  = __builtin_amdgcn_mfma_f32_16x16x32_bf16(P1, Vh1, c3, 0, 0, 0);
        c3  = __builtin_amdgcn_mfma_f32_16x16x32_bf16(P1, Vl1, c3, 0, 0, 0);
        la1 = __builtin_amdgcn_mfma_f32_16x16x32_bf16(P1, ONES, la1, 0, 0, 0);

        u16* w0 = plds[w][0][kp & 1];
        u16* w1 = plds[w][1][kp & 1];
#pragma unroll
        for (int r = 0; r < 4; ++r) {
            w0[(g * 4 + r) * 40 + m]      = pe0[r];
            w0[(g * 4 + r) * 40 + 16 + m] = pe0[4 + r];
            w1[(g * 4 + r) * 40 + m]      = pe1[r];
            w1[(g * 4 + r) * 40 + 16 + m] = pe1[4 + r];
        }

        KhA = nKhA; KlA = nKlA; KhB = nKhB; KlB = nKlB;
        Vh0 = nVh0; Vl0 = nVl0; Vh1 = nVh1; Vl1 = nVl1;
    }
    // epilogue: PV of kp=31 for both tiles
    {
        const short8 P0 = *(const short8*)&plds[w][0][31 & 1][m * 40 + g * 8];
        const short8 P1 = *(const short8*)&plds[w][1][31 & 1][m * 40 + g * 8];
        c0  = __builtin_amdgcn_mfma_f32_16x16x32_bf16(P0, Vh0, c0, 0, 0, 0);
        c0  = __builtin_amdgcn_mfma_f32_16x16x32_bf16(P0, Vl0, c0, 0, 0, 0);
        c1  = __builtin_amdgcn_mfma_f32_16x16x32_bf16(P0, Vh1, c1, 0, 0, 0);
        c1  = __builtin_amdgcn_mfma_f32_16x16x32_bf16(P0, Vl1, c1, 0, 0, 0);
        la0 = __builtin_amdgcn_mfma_f32_16x16x32_bf16(P0, ONES, la0, 0, 0, 0);
        c2  = __builtin_amdgcn_mfma_f32_16x16x32_bf16(P1, Vh0, c2, 0, 0, 0);
        c2  = __builtin_amdgcn_mfma_f32_16x16x32_bf16(P1, Vl0, c2, 0, 0, 0);
        c3  = __builtin_amdgcn_mfma_f32_16x16x32_bf16(P1, Vh1, c3, 0, 0, 0);
        c3  = __builtin_amdgcn_mfma_f32_16x16x32_bf16(P1, Vl1, c3, 0, 0, 0);
        la1 = __builtin_amdgcn_mfma_f32_16x16x32_bf16(P1, ONES, la1, 0, 0, 0);
    }
#undef S_BLOCK
#pragma unroll
    for (int r = 0; r < 4; ++r) {
        float li0 = __builtin_amdgcn_rcpf(la0[r]);
        float li1 = __builtin_amdgcn_rcpf(la1[r]);
        float* cr0 = ctx + (size_t)b * TT * DD + (size_t)(q0 + g * 4 + r) * DD;
        float* cr1 = ctx + (size_t)b * TT * DD + (size_t)(q0 + 16 + g * 4 + r) * DD;
        cr0[m]      = c0[r] * li0;
        cr0[16 + m] = c1[r] * li0;
        cr1[m]      = c2[r] * li1;
        cr1[16 + m] = c3[r] * li1;
    }
}

// ---------------------------------------------------------------------------
// Kernel 4: ymlp — R13 version, unchanged.
// ---------------------------------------------------------------------------
__global__ __launch_bounds__(256) void k_ymlp(const float* __restrict__ ctx,
                                              const float* __restrict__ h,
                                              const float* __restrict__ W1,
                                              const float* __restrict__ b1,
                                              const float* __restrict__ W2,
                                              const float* __restrict__ b2,
                                              float* __restrict__ out) {
    const int b = blockIdx.x;
    const int tid = threadIdx.x;
    __shared__ __align__(16) float cs[128 * DD];
    __shared__ __align__(16) float hs[128 * DD];
    const float* cb = ctx + (size_t)b * TT * DD;
    const float* hb = h + (size_t)b * TT * DD;
    const int e = tid & 31;
    const int d4 = (tid >> 5) * 4;
    float acc[4] = {0.f, 0.f, 0.f, 0.f};
    for (int kt = 0; kt < 8; ++kt) {
        const float4* s1 = (const float4*)(cb + (size_t)kt * 128 * DD);
        const float4* s2 = (const float4*)(hb + (size_t)kt * 128 * DD);
        float4* t1 = (float4*)cs;
        float4* t2 = (float4*)hs;
#pragma unroll
        for (int n = 0; n < 4; ++n) {
            t1[tid + n * 256] = s1[tid + n * 256];
            t2[tid + n * 256] = s2[tid + n * 256];
        }
        __syncthreads();
#pragma unroll 2
        for (int s = 0; s < 128; ++s) {
            float hv = hs[s * DD + e];
            float4 cv = *(const float4*)&cs[s * DD + d4];
            acc[0] = fmaf(cv.x, hv, acc[0]);
            acc[1] = fmaf(cv.y, hv, acc[1]);
            acc[2] = fmaf(cv.z, hv, acc[2]);
            acc[3] = fmaf(cv.w, hv, acc[3]);
        }
        __syncthreads();
    }
    __shared__ float ys[DD][DD];
#pragma unroll
    for (int r = 0; r < 4; ++r) ys[d4 + r][e] = acc[r];
    __syncthreads();
    __shared__ float yr[DD][33];
#pragma unroll
    for (int r = 0; r < 4; ++r) {
        float v = b1[e];
#pragma unroll
        for (int ee = 0; ee < DD; ++ee) v += ys[d4 + r][ee] * W1[ee * DD + e];
        yr[d4 + r][e] = fmaxf(v, 0.0f);
    }
    __syncthreads();
    if (tid < DD) {
        float v = b2[0];
#pragma unroll
        for (int ee = 0; ee < DD; ++ee) v += yr[tid][ee] * W2[ee];
        out[b * DD + tid] = 1.0f / (1.0f + expf(-v));
    }
}

// ---------------------------------------------------------------------------
extern "C" void kernel_launch(void* const* d_in, const int* in_sizes, int n_in,
                              void* d_out, int out_size, void* d_ws, size_t ws_size,
                              hipStream_t stream) {
    const int* ids   = (const int*)d_in[0];
    const float* emb = (const float*)d_in[1];
    const float* kl  = (const float*)d_in[2];
    const float* rk  = (const float*)d_in[3];
    const float* bl  = (const float*)d_in[4];
    const float* W1  = (const float*)d_in[5];
    const float* b1  = (const float*)d_in[6];
    const float* W2  = (const float*)d_in[7];
    const float* b2  = (const float*)d_in[8];
    float* out = (float*)d_out;

    char* ws = (char*)d_ws;
    const size_t H_ELEMS = (size_t)BB * TT * DD;   // 2,097,152
    u16* hh   = (u16*)ws;
    u16* hl   = (u16*)(ws + H_ELEMS * 2);
    u16* th   = (u16*)(ws + H_ELEMS * 4);
    u16* tl   = (u16*)(ws + H_ELEMS * 6);
    float* h  = (float*)(ws + H_ELEMS * 8);
    float* ctx = (float*)(ws + H_ELEMS * 8 + H_ELEMS * 4);
    int* list = (int*)(ws + H_ELEMS * 8 + H_ELEMS * 8);

    k_lstm_scan<<<BB + 1, 128, 0, stream>>>(ids, emb, kl, bl, rk, h,
                                            hh, hl, th, tl, list, out + BB * DD);
    k_attn<<<BB * 8, 256, 0, stream>>>(hh, hl, th, tl, ctx);
    k_ymlp<<<BB, 256, 0, stream>>>(ctx, h, W1, b1, W2, b2, out);
}